// Round 1
// baseline (10776.929 us; speedup 1.0000x reference)
//
#include <hip/hip_runtime.h>
#include <hip/hip_bf16.h>
#include <math.h>

#define EPSF 1e-12f
#define H 256
#define TSTEPS 4096
#define BATCH 32
#define TB (TSTEPS*BATCH)

// ---------------- block-wide sum over 256 threads (4 waves) ----------------
__device__ __forceinline__ float block_sum256(float v, float* red) {
  #pragma unroll
  for (int o = 32; o > 0; o >>= 1) v += __shfl_down(v, o, 64);
  __syncthreads();                       // protect red from previous use
  if ((threadIdx.x & 63) == 0) red[threadIdx.x >> 6] = v;
  __syncthreads();
  return red[0] + red[1] + red[2] + red[3];
}

// ---------------- kernel 1: spectral sigmas + normalized bias ----------------
// wsc[0..255] = b_sn, wsc[256] = 1/sigma_ih, wsc[257] = 1/sigma_hh
__global__ __launch_bounds__(256) void k_prep(
    const float* __restrict__ w_ih, const float* __restrict__ w_hh,
    const float* __restrict__ b_ih, const float* __restrict__ b_hh,
    const float* __restrict__ u_ih, const float* __restrict__ u_hh,
    float* __restrict__ wsc) {
  __shared__ float red[4];
  __shared__ float ubuf[H];
  __shared__ float vbuf[H];
  const int tid = threadIdx.x;

  float inv_sig[2];
  const float* Ws[2] = {w_ih, w_hh};
  const float* Us[2] = {u_ih, u_hh};
  #pragma unroll 1
  for (int m = 0; m < 2; m++) {
    const float* W = Ws[m];
    // u_n = u / (||u|| + eps)
    float uv = Us[m][tid];
    float nu = sqrtf(block_sum256(uv * uv, red));
    ubuf[tid] = uv / (nu + EPSF);
    __syncthreads();
    // v = l2norm(W^T @ u_n)   (column reads: coalesced across lanes)
    float vt = 0.f;
    for (int h = 0; h < H; h++) vt = fmaf(W[h * H + tid], ubuf[h], vt);
    float nv = sqrtf(block_sum256(vt * vt, red));
    vbuf[tid] = vt / (nv + EPSF);
    __syncthreads();
    // wv = W @ v ; sigma = ||wv||^2 / (||wv|| + eps)  (== u_new . wv exactly)
    float wv = 0.f;
    const float* wr = W + (size_t)tid * H;
    for (int i = 0; i < H; i++) wv = fmaf(wr[i], vbuf[i], wv);
    float n2 = block_sum256(wv * wv, red);
    float sigma = n2 / (sqrtf(n2) + EPSF);
    inv_sig[m] = 1.f / sigma;
  }
  // b_sn = b_ih/(||b_ih||+eps) + b_hh/(||b_hh||+eps)
  float bi = b_ih[tid], bh = b_hh[tid];
  float nbi = sqrtf(block_sum256(bi * bi, red));
  float nbh = sqrtf(block_sum256(bh * bh, red));
  wsc[tid] = bi / (nbi + EPSF) + bh / (nbh + EPSF);
  if (tid == 0) { wsc[H] = inv_sig[0]; wsc[H + 1] = inv_sig[1]; }
}

// ---------------- kernel 2: pre = x @ W_ih_sn^T + b_sn -> out[0:T*B*H] -------
// block handles 32 rows of (T*B); thread = output h column.
__global__ __launch_bounds__(256) void k_pre(
    const float* __restrict__ x, const float* __restrict__ w_ih,
    const float* __restrict__ wsc, float* __restrict__ pre) {
  __shared__ float xs[32 * 256];        // 32 KB x-tile
  const int tid = threadIdx.x;
  const size_t m0 = (size_t)blockIdx.x * 32;

  // stage 32 rows of x (coalesced float4)
  const float4* xp = (const float4*)(x + m0 * H);
  float4* xsv = (float4*)xs;
  #pragma unroll
  for (int j = 0; j < 8; j++) xsv[j * 256 + tid] = xp[j * 256 + tid];
  __syncthreads();

  float acc[32];
  #pragma unroll
  for (int m = 0; m < 32; m++) acc[m] = 0.f;

  const float* wrow = w_ih + (size_t)tid * H;
  #pragma unroll 1
  for (int kb = 0; kb < 256; kb += 8) {
    float4 wa = *(const float4*)(wrow + kb);
    float4 wb = *(const float4*)(wrow + kb + 4);
    #pragma unroll
    for (int m = 0; m < 32; m++) {
      const float* xr = xs + m * 256 + kb;
      float4 xa = *(const float4*)xr;        // LDS broadcast (all lanes same addr)
      float4 xb = *(const float4*)(xr + 4);
      float a = acc[m];
      a = fmaf(xa.x, wa.x, a); a = fmaf(xa.y, wa.y, a);
      a = fmaf(xa.z, wa.z, a); a = fmaf(xa.w, wa.w, a);
      a = fmaf(xb.x, wb.x, a); a = fmaf(xb.y, wb.y, a);
      a = fmaf(xb.z, wb.z, a); a = fmaf(xb.w, wb.w, a);
      acc[m] = a;
    }
  }
  const float inv_s = wsc[H];
  const float bsn = wsc[tid];
  #pragma unroll
  for (int m = 0; m < 32; m++)
    pre[(m0 + m) * H + tid] = fmaf(acc[m], inv_s, bsn);   // coalesced store
}

// ---------------- kernel 3: sequential scan, one block per batch element ----
// W_hh_sn row lives in VGPRs (256 regs/thread); h double-buffered in LDS.
// Reads pre from out[] and overwrites the same address with h_t (in-place).
__global__ __launch_bounds__(256, 1) void k_scan(
    const float* __restrict__ state, const float* __restrict__ w_hh,
    const float* __restrict__ wsc, float* __restrict__ out) {
  __shared__ __align__(16) float Hbuf[2][H];
  const int tid = threadIdx.x;
  const int b = blockIdx.x;
  const float inv_s = wsc[H + 1];

  // stage this thread's W row into registers, pre-scaled by 1/sigma
  float wreg[H];
  const float* wr = w_hh + (size_t)tid * H;
  #pragma unroll
  for (int k = 0; k < H; k += 4) {
    float4 wv = *(const float4*)(wr + k);
    wreg[k]     = wv.x * inv_s;
    wreg[k + 1] = wv.y * inv_s;
    wreg[k + 2] = wv.z * inv_s;
    wreg[k + 3] = wv.w * inv_s;
  }

  Hbuf[0][tid] = state[b * H + tid];
  float* outb = out + (size_t)b * H + tid;
  float pre_cur = outb[0];
  __syncthreads();

  float hn = 0.f;
  #pragma unroll 1
  for (int t = 0; t < TSTEPS; t++) {
    // prefetch next timestep's pre (last iter reads h_last region: discarded)
    float pre_next = outb[(size_t)(t + 1) * (BATCH * H)];

    const float* hb = Hbuf[t & 1];
    float acc = pre_cur;
    #pragma unroll
    for (int k = 0; k < H; k += 4) {
      float4 hq = *(const float4*)(hb + k);   // LDS broadcast
      acc = fmaf(wreg[k],     hq.x, acc);
      acc = fmaf(wreg[k + 1], hq.y, acc);
      acc = fmaf(wreg[k + 2], hq.z, acc);
      acc = fmaf(wreg[k + 3], hq.w, acc);
    }
    // tanh via fast exp, clamped so exp never overflows
    float ac = fminf(fmaxf(acc, -15.f), 15.f);
    float e = __expf(2.f * ac);
    hn = __fdividef(e - 1.f, e + 1.f);

    outb[(size_t)t * (BATCH * H)] = hn;       // overwrite pre slot with h_t
    Hbuf[(t + 1) & 1][tid] = hn;              // publish h for next step
    __syncthreads();                          // one barrier per step
    pre_cur = pre_next;
  }
  // h_last tail
  out[(size_t)TSTEPS * BATCH * H + b * H + tid] = hn;
}

// ---------------- launcher ---------------------------------------------------
extern "C" void kernel_launch(void* const* d_in, const int* in_sizes, int n_in,
                              void* d_out, int out_size, void* d_ws, size_t ws_size,
                              hipStream_t stream) {
  const float* x     = (const float*)d_in[0];
  const float* state = (const float*)d_in[1];
  const float* w_ih  = (const float*)d_in[2];
  const float* w_hh  = (const float*)d_in[3];
  const float* b_ih  = (const float*)d_in[4];
  const float* b_hh  = (const float*)d_in[5];
  const float* u_ih  = (const float*)d_in[6];
  const float* u_hh  = (const float*)d_in[7];
  float* out = (float*)d_out;
  float* wsc = (float*)d_ws;   // 258 floats of scratch

  k_prep<<<1, 256, 0, stream>>>(w_ih, w_hh, b_ih, b_hh, u_ih, u_hh, wsc);
  k_pre<<<TB / 32, 256, 0, stream>>>(x, w_ih, wsc, out);
  k_scan<<<BATCH, 256, 0, stream>>>(state, w_hh, wsc, out);
}

// Round 3
// 3666.764 us; speedup vs baseline: 2.9391x; 2.9391x over previous
//
#include <hip/hip_runtime.h>
#include <hip/hip_bf16.h>
#include <math.h>

#define EPSF 1e-12f
#define H 256
#define TSTEPS 4096
#define BATCH 32
#define TB (TSTEPS*BATCH)
#define BH (BATCH*H)

// ---------------- block-wide sum over 256 threads (4 waves) ----------------
__device__ __forceinline__ float block_sum256(float v, float* red) {
  #pragma unroll
  for (int o = 32; o > 0; o >>= 1) v += __shfl_down(v, o, 64);
  __syncthreads();                       // protect red from previous use
  if ((threadIdx.x & 63) == 0) red[threadIdx.x >> 6] = v;
  __syncthreads();
  return red[0] + red[1] + red[2] + red[3];
}

// ---------------- kernel 1: spectral sigmas + normalized bias ----------------
// wsc[0..255] = b_sn, wsc[256] = 1/sigma_ih, wsc[257] = 1/sigma_hh
__global__ __launch_bounds__(256) void k_prep(
    const float* __restrict__ w_ih, const float* __restrict__ w_hh,
    const float* __restrict__ b_ih, const float* __restrict__ b_hh,
    const float* __restrict__ u_ih, const float* __restrict__ u_hh,
    float* __restrict__ wsc) {
  __shared__ float red[4];
  __shared__ float ubuf[H];
  __shared__ float vbuf[H];
  const int tid = threadIdx.x;

  float inv_sig[2];
  const float* Ws[2] = {w_ih, w_hh};
  const float* Us[2] = {u_ih, u_hh};
  #pragma unroll 1
  for (int m = 0; m < 2; m++) {
    const float* W = Ws[m];
    // u_n = u / (||u|| + eps)
    float uv = Us[m][tid];
    float nu = sqrtf(block_sum256(uv * uv, red));
    ubuf[tid] = uv / (nu + EPSF);
    __syncthreads();
    // v = l2norm(W^T @ u_n)   (column reads: coalesced across lanes)
    float vt = 0.f;
    for (int h = 0; h < H; h++) vt = fmaf(W[h * H + tid], ubuf[h], vt);
    float nv = sqrtf(block_sum256(vt * vt, red));
    vbuf[tid] = vt / (nv + EPSF);
    __syncthreads();
    // wv = W @ v ; sigma = ||wv||^2 / (||wv|| + eps)  (== u_new . wv exactly)
    float wv = 0.f;
    const float* wr = W + (size_t)tid * H;
    for (int i = 0; i < H; i++) wv = fmaf(wr[i], vbuf[i], wv);
    float n2 = block_sum256(wv * wv, red);
    float sigma = n2 / (sqrtf(n2) + EPSF);
    inv_sig[m] = 1.f / sigma;
  }
  // b_sn = b_ih/(||b_ih||+eps) + b_hh/(||b_hh||+eps)
  float bi = b_ih[tid], bh = b_hh[tid];
  float nbi = sqrtf(block_sum256(bi * bi, red));
  float nbh = sqrtf(block_sum256(bh * bh, red));
  wsc[tid] = bi / (nbi + EPSF) + bh / (nbh + EPSF);
  if (tid == 0) { wsc[H] = inv_sig[0]; wsc[H + 1] = inv_sig[1]; }
}

// ---------------- kernel 2: pre = x @ W_ih_sn^T + b_sn -> out[0:T*B*H] -------
// block handles 32 rows of (T*B); thread = output h column.
__global__ __launch_bounds__(256) void k_pre(
    const float* __restrict__ x, const float* __restrict__ w_ih,
    const float* __restrict__ wsc, float* __restrict__ pre) {
  __shared__ float xs[32 * 256];        // 32 KB x-tile
  const int tid = threadIdx.x;
  const size_t m0 = (size_t)blockIdx.x * 32;

  // stage 32 rows of x (coalesced float4)
  const float4* xp = (const float4*)(x + m0 * H);
  float4* xsv = (float4*)xs;
  #pragma unroll
  for (int j = 0; j < 8; j++) xsv[j * 256 + tid] = xp[j * 256 + tid];
  __syncthreads();

  float acc[32];
  #pragma unroll
  for (int m = 0; m < 32; m++) acc[m] = 0.f;

  const float* wrow = w_ih + (size_t)tid * H;
  #pragma unroll 1
  for (int kb = 0; kb < 256; kb += 8) {
    float4 wa = *(const float4*)(wrow + kb);
    float4 wb = *(const float4*)(wrow + kb + 4);
    #pragma unroll
    for (int m = 0; m < 32; m++) {
      const float* xr = xs + m * 256 + kb;
      float4 xa = *(const float4*)xr;        // LDS broadcast (all lanes same addr)
      float4 xb = *(const float4*)(xr + 4);
      float a = acc[m];
      a = fmaf(xa.x, wa.x, a); a = fmaf(xa.y, wa.y, a);
      a = fmaf(xa.z, wa.z, a); a = fmaf(xa.w, wa.w, a);
      a = fmaf(xb.x, wb.x, a); a = fmaf(xb.y, wb.y, a);
      a = fmaf(xb.z, wb.z, a); a = fmaf(xb.w, wb.w, a);
      acc[m] = a;
    }
  }
  const float inv_s = wsc[H];
  const float bsn = wsc[tid];
  #pragma unroll
  for (int m = 0; m < 32; m++)
    pre[(m0 + m) * H + tid] = fmaf(acc[m], inv_s, bsn);   // coalesced store
}

// ---------------- kernel 3: sequential scan, one block per batch element ----
// 1024 threads = 16 waves. Thread (cg,r): cg=tid>>8 covers h-columns
// [cg*64, cg*64+64), r=tid&255 is the output row. W slice = 16 float4 =
// 64 VGPRs (no spill risk — R1 fix: 256-float array spilled, VGPR=136).
// h broadcast from LDS; 4 partials reduced via LDS; cg==0 does tanh+store.
// R2 fix: launcher was still passing 256 threads — must be 1024.
__global__ __launch_bounds__(1024, 4) void k_scan(
    const float* __restrict__ state, const float* __restrict__ w_hh,
    const float* __restrict__ wsc, float* __restrict__ out) {
  __shared__ __align__(16) float hbuf[2][H];
  __shared__ float part[4][H];
  const int tid = threadIdx.x;
  const int cg = tid >> 8;       // 0..3
  const int r  = tid & 255;      // output row
  const int b = blockIdx.x;
  const float inv_s = wsc[H + 1];

  // stage W[r][cg*64 .. +63] into registers, pre-scaled by 1/sigma
  float4 wreg[16];
  const float* wr = w_hh + (size_t)r * H + (cg << 6);
  #pragma unroll
  for (int j = 0; j < 16; j++) {
    float4 wv = *(const float4*)(wr + j * 4);
    wreg[j] = make_float4(wv.x * inv_s, wv.y * inv_s, wv.z * inv_s, wv.w * inv_s);
  }

  if (tid < H) hbuf[0][tid] = state[b * H + tid];
  float* outb = out + (size_t)b * H + r;
  float pre0 = 0.f, pre1 = 0.f;
  if (cg == 0) { pre0 = outb[0]; pre1 = outb[BH]; }   // prefetch depth 2
  __syncthreads();

  float hn = 0.f;
  #pragma unroll 1
  for (int t = 0; t < TSTEPS; t++) {
    float pre2 = 0.f;
    if (cg == 0) {                       // wave-uniform branch (waves 0..3)
      int tn = (t + 2 <= TSTEPS) ? (t + 2) : TSTEPS;   // clamp into h_last region
      pre2 = outb[(size_t)tn * BH];
    }

    const float4* hb = (const float4*)(hbuf[t & 1] + (cg << 6));
    float acc = 0.f;
    #pragma unroll
    for (int j = 0; j < 16; j++) {
      float4 hq = hb[j];                 // LDS broadcast (wave-uniform addr)
      acc = fmaf(wreg[j].x, hq.x, acc);
      acc = fmaf(wreg[j].y, hq.y, acc);
      acc = fmaf(wreg[j].z, hq.z, acc);
      acc = fmaf(wreg[j].w, hq.w, acc);
    }
    part[cg][r] = acc;                   // conflict-free (consecutive addrs)
    __syncthreads();

    if (cg == 0) {
      float s = part[0][r] + part[1][r] + part[2][r] + part[3][r] + pre0;
      float sc = fminf(fmaxf(s, -15.f), 15.f);
      float e = __expf(2.f * sc);
      hn = __fdividef(e - 1.f, e + 1.f); // tanh
      outb[(size_t)t * BH] = hn;         // overwrite pre slot with h_t
      hbuf[(t + 1) & 1][r] = hn;         // publish h for next step
    }
    __syncthreads();
    pre0 = pre1; pre1 = pre2;
  }
  if (cg == 0) out[(size_t)TSTEPS * BH + b * H + r] = hn;  // h_last tail
}

// ---------------- launcher ---------------------------------------------------
extern "C" void kernel_launch(void* const* d_in, const int* in_sizes, int n_in,
                              void* d_out, int out_size, void* d_ws, size_t ws_size,
                              hipStream_t stream) {
  const float* x     = (const float*)d_in[0];
  const float* state = (const float*)d_in[1];
  const float* w_ih  = (const float*)d_in[2];
  const float* w_hh  = (const float*)d_in[3];
  const float* b_ih  = (const float*)d_in[4];
  const float* b_hh  = (const float*)d_in[5];
  const float* u_ih  = (const float*)d_in[6];
  const float* u_hh  = (const float*)d_in[7];
  float* out = (float*)d_out;
  float* wsc = (float*)d_ws;   // 258 floats of scratch

  k_prep<<<1, 256, 0, stream>>>(w_ih, w_hh, b_ih, b_hh, u_ih, u_hh, wsc);
  k_pre<<<TB / 32, 256, 0, stream>>>(x, w_ih, wsc, out);
  k_scan<<<BATCH, 1024, 0, stream>>>(state, w_hh, wsc, out);   // R2 fix: 1024 thr
}

// Round 4
// 2860.255 us; speedup vs baseline: 3.7678x; 1.2820x over previous
//
#include <hip/hip_runtime.h>
#include <hip/hip_bf16.h>
#include <math.h>

#define EPSF 1e-12f
#define H 256
#define TSTEPS 4096
#define BATCH 32
#define TB (TSTEPS*BATCH)
#define BH (BATCH*H)

typedef _Float16 h2 __attribute__((ext_vector_type(2)));

#if defined(__has_builtin)
#if __has_builtin(__builtin_amdgcn_fdot2)
#define FDOT2(a, b, c) __builtin_amdgcn_fdot2((a), (b), (c), false)
#endif
#endif
#ifndef FDOT2
#define FDOT2(a, b, c) fmaf((float)(a).y, (float)(b).y, fmaf((float)(a).x, (float)(b).x, (c)))
#endif

// ---------------- block-wide sum over 256 threads (4 waves) ----------------
__device__ __forceinline__ float block_sum256(float v, float* red) {
  #pragma unroll
  for (int o = 32; o > 0; o >>= 1) v += __shfl_down(v, o, 64);
  __syncthreads();                       // protect red from previous use
  if ((threadIdx.x & 63) == 0) red[threadIdx.x >> 6] = v;
  __syncthreads();
  return red[0] + red[1] + red[2] + red[3];
}

// ---------------- kernel 1: spectral sigmas + normalized bias ----------------
// wsc[0..255] = b_sn, wsc[256] = 1/sigma_ih, wsc[257] = 1/sigma_hh
__global__ __launch_bounds__(256) void k_prep(
    const float* __restrict__ w_ih, const float* __restrict__ w_hh,
    const float* __restrict__ b_ih, const float* __restrict__ b_hh,
    const float* __restrict__ u_ih, const float* __restrict__ u_hh,
    float* __restrict__ wsc) {
  __shared__ float red[4];
  __shared__ float ubuf[H];
  __shared__ float vbuf[H];
  const int tid = threadIdx.x;

  float inv_sig[2];
  const float* Ws[2] = {w_ih, w_hh};
  const float* Us[2] = {u_ih, u_hh};
  #pragma unroll 1
  for (int m = 0; m < 2; m++) {
    const float* W = Ws[m];
    // u_n = u / (||u|| + eps)
    float uv = Us[m][tid];
    float nu = sqrtf(block_sum256(uv * uv, red));
    ubuf[tid] = uv / (nu + EPSF);
    __syncthreads();
    // v = l2norm(W^T @ u_n)   (column reads: coalesced across lanes)
    float vt = 0.f;
    for (int h = 0; h < H; h++) vt = fmaf(W[h * H + tid], ubuf[h], vt);
    float nv = sqrtf(block_sum256(vt * vt, red));
    vbuf[tid] = vt / (nv + EPSF);
    __syncthreads();
    // wv = W @ v ; sigma = ||wv||^2 / (||wv|| + eps)  (== u_new . wv exactly)
    float wv = 0.f;
    const float* wr = W + (size_t)tid * H;
    for (int i = 0; i < H; i++) wv = fmaf(wr[i], vbuf[i], wv);
    float n2 = block_sum256(wv * wv, red);
    float sigma = n2 / (sqrtf(n2) + EPSF);
    inv_sig[m] = 1.f / sigma;
  }
  // b_sn = b_ih/(||b_ih||+eps) + b_hh/(||b_hh||+eps)
  float bi = b_ih[tid], bh = b_hh[tid];
  float nbi = sqrtf(block_sum256(bi * bi, red));
  float nbh = sqrtf(block_sum256(bh * bh, red));
  wsc[tid] = bi / (nbi + EPSF) + bh / (nbh + EPSF);
  if (tid == 0) { wsc[H] = inv_sig[0]; wsc[H + 1] = inv_sig[1]; }
}

// ---------------- kernel 2: pre = x @ W_ih_sn^T + b_sn -> out[0:T*B*H] -------
// block handles 32 rows of (T*B); thread = output h column.
__global__ __launch_bounds__(256) void k_pre(
    const float* __restrict__ x, const float* __restrict__ w_ih,
    const float* __restrict__ wsc, float* __restrict__ pre) {
  __shared__ float xs[32 * 256];        // 32 KB x-tile
  const int tid = threadIdx.x;
  const size_t m0 = (size_t)blockIdx.x * 32;

  // stage 32 rows of x (coalesced float4)
  const float4* xp = (const float4*)(x + m0 * H);
  float4* xsv = (float4*)xs;
  #pragma unroll
  for (int j = 0; j < 8; j++) xsv[j * 256 + tid] = xp[j * 256 + tid];
  __syncthreads();

  float acc[32];
  #pragma unroll
  for (int m = 0; m < 32; m++) acc[m] = 0.f;

  const float* wrow = w_ih + (size_t)tid * H;
  #pragma unroll 1
  for (int kb = 0; kb < 256; kb += 8) {
    float4 wa = *(const float4*)(wrow + kb);
    float4 wb = *(const float4*)(wrow + kb + 4);
    #pragma unroll
    for (int m = 0; m < 32; m++) {
      const float* xr = xs + m * 256 + kb;
      float4 xa = *(const float4*)xr;        // LDS broadcast (all lanes same addr)
      float4 xb = *(const float4*)(xr + 4);
      float a = acc[m];
      a = fmaf(xa.x, wa.x, a); a = fmaf(xa.y, wa.y, a);
      a = fmaf(xa.z, wa.z, a); a = fmaf(xa.w, wa.w, a);
      a = fmaf(xb.x, wb.x, a); a = fmaf(xb.y, wb.y, a);
      a = fmaf(xb.z, wb.z, a); a = fmaf(xb.w, wb.w, a);
      acc[m] = a;
    }
  }
  const float inv_s = wsc[H];
  const float bsn = wsc[tid];
  #pragma unroll
  for (int m = 0; m < 32; m++)
    pre[(m0 + m) * H + tid] = fmaf(acc[m], inv_s, bsn);   // coalesced store
}

// ---------------- kernel 3: sequential scan, one block per batch element ----
// 1024 threads = 16 waves. Thread (cg,r): cg=tid>>8 covers h-columns
// [cg*64, cg*64+64), r=tid&255 is the output row.
// R4: W slice and h in f16, v_dot2_f32_f16 (f32 accumulate). Halves VGPR
// footprint (32 packed regs — R3's VGPR=52 showed the f32 version never
// achieved register residency), LDS broadcast traffic, and VALU issue.
__global__ __launch_bounds__(1024, 4) void k_scan(
    const float* __restrict__ state, const float* __restrict__ w_hh,
    const float* __restrict__ wsc, float* __restrict__ out) {
  __shared__ __align__(16) _Float16 hbuf[2][H];   // 512 B per buffer
  __shared__ float part[4][H];
  const int tid = threadIdx.x;
  const int cg = tid >> 8;       // 0..3
  const int r  = tid & 255;      // output row
  const int b = blockIdx.x;
  const float inv_s = wsc[H + 1];

  // stage W[r][cg*64 .. +63] as 32 packed f16x2, pre-scaled by 1/sigma
  h2 wreg[32];
  const float* wr = w_hh + (size_t)r * H + (cg << 6);
  #pragma unroll
  for (int j = 0; j < 16; j++) {
    float4 wv = *(const float4*)(wr + j * 4);
    wreg[2 * j]     = h2{(_Float16)(wv.x * inv_s), (_Float16)(wv.y * inv_s)};
    wreg[2 * j + 1] = h2{(_Float16)(wv.z * inv_s), (_Float16)(wv.w * inv_s)};
  }

  if (tid < H) hbuf[0][tid] = (_Float16)state[b * H + tid];
  float* outb = out + (size_t)b * H + r;
  float pre0 = 0.f, pre1 = 0.f;
  if (cg == 0) { pre0 = outb[0]; pre1 = outb[BH]; }   // prefetch depth 2
  __syncthreads();

  float hn = 0.f;
  #pragma unroll 1
  for (int t = 0; t < TSTEPS; t++) {
    float pre2 = 0.f;
    if (cg == 0) {                       // wave-uniform branch (waves 0..3)
      int tn = (t + 2 <= TSTEPS) ? (t + 2) : TSTEPS;   // clamp into h_last region
      pre2 = outb[(size_t)tn * BH];
    }

    // 64 f16 h-values = 8 uint4 LDS broadcast reads (wave-uniform addr)
    const uint4* hb = (const uint4*)(hbuf[t & 1] + (cg << 6));
    float acc = 0.f;
    #pragma unroll
    for (int j = 0; j < 8; j++) {
      uint4 q = hb[j];
      acc = FDOT2(wreg[4 * j + 0], __builtin_bit_cast(h2, q.x), acc);
      acc = FDOT2(wreg[4 * j + 1], __builtin_bit_cast(h2, q.y), acc);
      acc = FDOT2(wreg[4 * j + 2], __builtin_bit_cast(h2, q.z), acc);
      acc = FDOT2(wreg[4 * j + 3], __builtin_bit_cast(h2, q.w), acc);
    }
    part[cg][r] = acc;                   // conflict-free (consecutive addrs)
    __syncthreads();

    if (cg == 0) {
      float s = part[0][r] + part[1][r] + part[2][r] + part[3][r] + pre0;
      float sc = fminf(fmaxf(s, -15.f), 15.f);
      float e = __expf(2.f * sc);
      hn = __fdividef(e - 1.f, e + 1.f); // tanh
      outb[(size_t)t * BH] = hn;         // overwrite pre slot with h_t (f32)
      hbuf[(t + 1) & 1][r] = (_Float16)hn;  // publish f16 h for next step
    }
    __syncthreads();
    pre0 = pre1; pre1 = pre2;
  }
  if (cg == 0) out[(size_t)TSTEPS * BH + b * H + r] = hn;  // h_last tail
}

// ---------------- launcher ---------------------------------------------------
extern "C" void kernel_launch(void* const* d_in, const int* in_sizes, int n_in,
                              void* d_out, int out_size, void* d_ws, size_t ws_size,
                              hipStream_t stream) {
  const float* x     = (const float*)d_in[0];
  const float* state = (const float*)d_in[1];
  const float* w_ih  = (const float*)d_in[2];
  const float* w_hh  = (const float*)d_in[3];
  const float* b_ih  = (const float*)d_in[4];
  const float* b_hh  = (const float*)d_in[5];
  const float* u_ih  = (const float*)d_in[6];
  const float* u_hh  = (const float*)d_in[7];
  float* out = (float*)d_out;
  float* wsc = (float*)d_ws;   // 258 floats of scratch

  k_prep<<<1, 256, 0, stream>>>(w_ih, w_hh, b_ih, b_hh, u_ih, u_hh, wsc);
  k_pre<<<TB / 32, 256, 0, stream>>>(x, w_ih, wsc, out);
  k_scan<<<BATCH, 1024, 0, stream>>>(state, w_hh, wsc, out);
}

// Round 5
// 2711.439 us; speedup vs baseline: 3.9746x; 1.0549x over previous
//
#include <hip/hip_runtime.h>
#include <hip/hip_bf16.h>
#include <math.h>

#define EPSF 1e-12f
#define H 256
#define TSTEPS 4096
#define BATCH 32
#define TB (TSTEPS*BATCH)
#define BH (BATCH*H)

typedef _Float16 h2 __attribute__((ext_vector_type(2)));

#if defined(__has_builtin)
#if __has_builtin(__builtin_amdgcn_fdot2)
#define FDOT2(a, b, c) __builtin_amdgcn_fdot2((a), (b), (c), false)
#endif
#endif
#ifndef FDOT2
#define FDOT2(a, b, c) fmaf((float)(a).y, (float)(b).y, fmaf((float)(a).x, (float)(b).x, (c)))
#endif

#define BC(u) __builtin_bit_cast(h2, (u))

// ---------------- block-wide sum over 256 threads (4 waves) ----------------
__device__ __forceinline__ float block_sum256(float v, float* red) {
  #pragma unroll
  for (int o = 32; o > 0; o >>= 1) v += __shfl_down(v, o, 64);
  __syncthreads();                       // protect red from previous use
  if ((threadIdx.x & 63) == 0) red[threadIdx.x >> 6] = v;
  __syncthreads();
  return red[0] + red[1] + red[2] + red[3];
}

// ---------------- kernel 1: spectral sigmas + normalized bias ----------------
// wsc[0..255] = b_sn, wsc[256] = 1/sigma_ih, wsc[257] = 1/sigma_hh
__global__ __launch_bounds__(256) void k_prep(
    const float* __restrict__ w_ih, const float* __restrict__ w_hh,
    const float* __restrict__ b_ih, const float* __restrict__ b_hh,
    const float* __restrict__ u_ih, const float* __restrict__ u_hh,
    float* __restrict__ wsc) {
  __shared__ float red[4];
  __shared__ float ubuf[H];
  __shared__ float vbuf[H];
  const int tid = threadIdx.x;

  float inv_sig[2];
  const float* Ws[2] = {w_ih, w_hh};
  const float* Us[2] = {u_ih, u_hh};
  #pragma unroll 1
  for (int m = 0; m < 2; m++) {
    const float* W = Ws[m];
    // u_n = u / (||u|| + eps)
    float uv = Us[m][tid];
    float nu = sqrtf(block_sum256(uv * uv, red));
    ubuf[tid] = uv / (nu + EPSF);
    __syncthreads();
    // v = l2norm(W^T @ u_n)   (column reads: coalesced across lanes)
    float vt = 0.f;
    for (int h = 0; h < H; h++) vt = fmaf(W[h * H + tid], ubuf[h], vt);
    float nv = sqrtf(block_sum256(vt * vt, red));
    vbuf[tid] = vt / (nv + EPSF);
    __syncthreads();
    // wv = W @ v ; sigma = ||wv||^2 / (||wv|| + eps)  (== u_new . wv exactly)
    float wv = 0.f;
    const float* wr = W + (size_t)tid * H;
    for (int i = 0; i < H; i++) wv = fmaf(wr[i], vbuf[i], wv);
    float n2 = block_sum256(wv * wv, red);
    float sigma = n2 / (sqrtf(n2) + EPSF);
    inv_sig[m] = 1.f / sigma;
  }
  // b_sn = b_ih/(||b_ih||+eps) + b_hh/(||b_hh||+eps)
  float bi = b_ih[tid], bh = b_hh[tid];
  float nbi = sqrtf(block_sum256(bi * bi, red));
  float nbh = sqrtf(block_sum256(bh * bh, red));
  wsc[tid] = bi / (nbi + EPSF) + bh / (nbh + EPSF);
  if (tid == 0) { wsc[H] = inv_sig[0]; wsc[H + 1] = inv_sig[1]; }
}

// ---------------- kernel 2: pre = x @ W_ih_sn^T + b_sn -> out[0:T*B*H] -------
// block handles 32 rows of (T*B); thread = output h column.
__global__ __launch_bounds__(256) void k_pre(
    const float* __restrict__ x, const float* __restrict__ w_ih,
    const float* __restrict__ wsc, float* __restrict__ pre) {
  __shared__ float xs[32 * 256];        // 32 KB x-tile
  const int tid = threadIdx.x;
  const size_t m0 = (size_t)blockIdx.x * 32;

  // stage 32 rows of x (coalesced float4)
  const float4* xp = (const float4*)(x + m0 * H);
  float4* xsv = (float4*)xs;
  #pragma unroll
  for (int j = 0; j < 8; j++) xsv[j * 256 + tid] = xp[j * 256 + tid];
  __syncthreads();

  float acc[32];
  #pragma unroll
  for (int m = 0; m < 32; m++) acc[m] = 0.f;

  const float* wrow = w_ih + (size_t)tid * H;
  #pragma unroll 1
  for (int kb = 0; kb < 256; kb += 8) {
    float4 wa = *(const float4*)(wrow + kb);
    float4 wb = *(const float4*)(wrow + kb + 4);
    #pragma unroll
    for (int m = 0; m < 32; m++) {
      const float* xr = xs + m * 256 + kb;
      float4 xa = *(const float4*)xr;        // LDS broadcast (all lanes same addr)
      float4 xb = *(const float4*)(xr + 4);
      float a = acc[m];
      a = fmaf(xa.x, wa.x, a); a = fmaf(xa.y, wa.y, a);
      a = fmaf(xa.z, wa.z, a); a = fmaf(xa.w, wa.w, a);
      a = fmaf(xb.x, wb.x, a); a = fmaf(xb.y, wb.y, a);
      a = fmaf(xb.z, wb.z, a); a = fmaf(xb.w, wb.w, a);
      acc[m] = a;
    }
  }
  const float inv_s = wsc[H];
  const float bsn = wsc[tid];
  #pragma unroll
  for (int m = 0; m < 32; m++)
    pre[(m0 + m) * H + tid] = fmaf(acc[m], inv_s, bsn);   // coalesced store
}

// ---------------- kernel 3: sequential scan, one block per batch element ----
// R5: LDS-broadcast traffic is the limiter (R4: 128 KB/step ≈ 1359 cy).
// 512 threads = 8 waves; wave cg owns 32 h-columns; lane q owns 4 rows
// (4q..4q+3). Each loaded h value feeds 4 dot products (4x LDS traffic cut:
// 32 KB/step). W slice = 4x16 h2 = 64 VGPRs. part[8][256] reduced by
// 256 threads (thread = row), conflict-free both phases.
__global__ __launch_bounds__(512, 1) void k_scan(
    const float* __restrict__ state, const float* __restrict__ w_hh,
    const float* __restrict__ wsc, float* __restrict__ out) {
  __shared__ __align__(16) _Float16 hbuf[2][H];   // 512 B each
  __shared__ __align__(16) float part[8][H];      // 8 KB
  const int tid = threadIdx.x;
  const int cg = tid >> 6;       // 0..7 == wave id == col group (32 cols)
  const int q  = tid & 63;       // lane; owns rows 4q..4q+3
  const int r0 = q << 2;
  const int b = blockIdx.x;
  const float inv_s = wsc[H + 1];

  // stage W[4q+i][cg*32 .. +31] as 4x16 packed f16x2, pre-scaled by 1/sigma
  h2 wreg[4][16];
  #pragma unroll
  for (int i = 0; i < 4; i++) {
    const float* wr = w_hh + (size_t)(r0 + i) * H + (cg << 5);
    #pragma unroll
    for (int c = 0; c < 16; c++) {
      float2 wv = *(const float2*)(wr + 2 * c);
      wreg[i][c] = h2{(_Float16)(wv.x * inv_s), (_Float16)(wv.y * inv_s)};
    }
  }

  if (tid < H) hbuf[0][tid] = (_Float16)state[b * H + tid];
  float* outb = out + (size_t)b * H + tid;       // only dereferenced if tid<H
  float pre0 = 0.f, pre1 = 0.f;
  if (tid < H) { pre0 = outb[0]; pre1 = outb[BH]; }   // prefetch depth 2
  __syncthreads();

  float hn = 0.f;
  #pragma unroll 1
  for (int t = 0; t < TSTEPS; t++) {
    float pre2 = 0.f;
    if (tid < H) {
      int tn = (t + 2 <= TSTEPS) ? (t + 2) : TSTEPS;   // clamp into h_last region
      pre2 = outb[(size_t)tn * BH];
    }

    // 32 f16 h-values = 4 uint4 LDS broadcast reads (wave-uniform addr)
    const uint4* hb = (const uint4*)(hbuf[t & 1] + (cg << 5));
    uint4 q0 = hb[0], q1 = hb[1], q2 = hb[2], q3 = hb[3];

    float acc[4];
    #pragma unroll
    for (int i = 0; i < 4; i++) {
      float a = 0.f;
      a = FDOT2(wreg[i][ 0], BC(q0.x), a);
      a = FDOT2(wreg[i][ 1], BC(q0.y), a);
      a = FDOT2(wreg[i][ 2], BC(q0.z), a);
      a = FDOT2(wreg[i][ 3], BC(q0.w), a);
      a = FDOT2(wreg[i][ 4], BC(q1.x), a);
      a = FDOT2(wreg[i][ 5], BC(q1.y), a);
      a = FDOT2(wreg[i][ 6], BC(q1.z), a);
      a = FDOT2(wreg[i][ 7], BC(q1.w), a);
      a = FDOT2(wreg[i][ 8], BC(q2.x), a);
      a = FDOT2(wreg[i][ 9], BC(q2.y), a);
      a = FDOT2(wreg[i][10], BC(q2.z), a);
      a = FDOT2(wreg[i][11], BC(q2.w), a);
      a = FDOT2(wreg[i][12], BC(q3.x), a);
      a = FDOT2(wreg[i][13], BC(q3.y), a);
      a = FDOT2(wreg[i][14], BC(q3.z), a);
      a = FDOT2(wreg[i][15], BC(q3.w), a);
      acc[i] = a;
    }
    // conflict-free b128 store: lanes write contiguous 16B (part[cg][4q..4q+3])
    *(float4*)&part[cg][r0] = make_float4(acc[0], acc[1], acc[2], acc[3]);
    __syncthreads();

    if (tid < H) {                       // thread = row; 2-way-free b32 reads
      float s = pre0;
      #pragma unroll
      for (int g = 0; g < 8; g++) s += part[g][tid];
      float sc = fminf(fmaxf(s, -15.f), 15.f);
      float e = __expf(2.f * sc);
      hn = __fdividef(e - 1.f, e + 1.f); // tanh
      outb[(size_t)t * BH] = hn;         // overwrite pre slot with h_t (f32)
      hbuf[(t + 1) & 1][tid] = (_Float16)hn;  // publish f16 h for next step
    }
    __syncthreads();
    pre0 = pre1; pre1 = pre2;
  }
  if (tid < H) out[(size_t)TSTEPS * BH + b * H + tid] = hn;  // h_last tail
}

// ---------------- launcher ---------------------------------------------------
extern "C" void kernel_launch(void* const* d_in, const int* in_sizes, int n_in,
                              void* d_out, int out_size, void* d_ws, size_t ws_size,
                              hipStream_t stream) {
  const float* x     = (const float*)d_in[0];
  const float* state = (const float*)d_in[1];
  const float* w_ih  = (const float*)d_in[2];
  const float* w_hh  = (const float*)d_in[3];
  const float* b_ih  = (const float*)d_in[4];
  const float* b_hh  = (const float*)d_in[5];
  const float* u_ih  = (const float*)d_in[6];
  const float* u_hh  = (const float*)d_in[7];
  float* out = (float*)d_out;
  float* wsc = (float*)d_ws;   // 258 floats of scratch

  k_prep<<<1, 256, 0, stream>>>(w_ih, w_hh, b_ih, b_hh, u_ih, u_hh, wsc);
  k_pre<<<TB / 32, 256, 0, stream>>>(x, w_ih, wsc, out);
  k_scan<<<BATCH, 512, 0, stream>>>(state, w_hh, wsc, out);
}